// Round 1
// baseline (1596.757 us; speedup 1.0000x reference)
//
#include <hip/hip_runtime.h>
#include <hip/hip_fp16.h>
#include <stdint.h>

// Problem constants (B,L,E,H,D) = (4,2048,1024,16,64)
#define Bc 4
#define Lc 2048
#define Ec 1024
#define Hc 16
#define Dc 64

typedef __attribute__((ext_vector_type(4))) float float4v;
typedef __attribute__((ext_vector_type(8))) _Float16 half8;
typedef __attribute__((ext_vector_type(4))) _Float16 half4;

__device__ __forceinline__ void async_copy16(void* lds, const void* g) {
  __builtin_amdgcn_global_load_lds(
      (const __attribute__((address_space(1))) void*)g,
      (__attribute__((address_space(3))) void*)lds, 16, 0, 0);
}

// ---------------- fp32 -> fp16 conversion ----------------
__global__ void cvt_kernel(const float* __restrict__ src, _Float16* __restrict__ dst, int n4) {
  int i = blockIdx.x * 256 + threadIdx.x;
  if (i >= n4) return;
  float4v v = ((const float4v*)src)[i];
  half4 h;
  h[0] = (_Float16)v[0]; h[1] = (_Float16)v[1];
  h[2] = (_Float16)v[2]; h[3] = (_Float16)v[3];
  ((half4*)dst)[i] = h;
}

// ---------------- GEMM: C[m,n] = sum_k A[m,k]*B[n,k]  (both K-contiguous) ---
// M=8192, N=1024, K=1024. 128x128 tile, BK=32, 4 waves (2x2), 16x16x32 MFMA.
// EPI 0: fp16 out at [b,h,l,d] (b=m/2048,l=m%2048,h=n/64,d=n%64)
// EPI 1: fp16 out at [b,h,d,l] (transposed V for PV's B-operand)
// EPI 2: fp32 out at m*1024+n
template<int EPI>
__global__ __launch_bounds__(256, 2) void gemm_bt(const _Float16* __restrict__ A,
                                                  const _Float16* __restrict__ Bw,
                                                  void* __restrict__ Cout) {
  __shared__ __align__(16) _Float16 As[128 * 32];
  __shared__ __align__(16) _Float16 Bs[128 * 32];
  const int tid = threadIdx.x;
  const int w = tid >> 6, lane = tid & 63, lr = lane & 15, lq = lane >> 4;
  const int wm = w & 1, wn = w >> 1;
  const int mB = blockIdx.y, nB = blockIdx.x;

  // staging: thread t covers LDS slot row rA=t/4 (+64 for 2nd inst), chunk t%4.
  // XOR-ish swizzle: slot chunk c' holds global chunk (c' - f(r)) & 3, f(r)=(r+r/4)&3
  const int rA = tid >> 2;
  const int fsw = (rA + (rA >> 2)) & 3;
  const int cg = ((tid & 3) - fsw) & 3;
  const _Float16* Ag = A + (size_t)(mB * 128 + rA) * 1024 + cg * 8;
  const _Float16* Bg = Bw + (size_t)(nB * 128 + rA) * 1024 + cg * 8;
  char* ldsA = (char*)As + (tid >> 6) * 1024;  // + lane*16 added by HW
  char* ldsB = (char*)Bs + (tid >> 6) * 1024;

  int aoff[4], boff[4];
#pragma unroll
  for (int i = 0; i < 4; i++) {
    int Ra = wm * 64 + i * 16 + lr;
    aoff[i] = Ra * 32 + ((lq + (Ra & 63) + ((Ra & 63) >> 2)) & 3) * 8;
    int Rb = wn * 64 + i * 16 + lr;
    boff[i] = Rb * 32 + ((lq + (Rb & 63) + ((Rb & 63) >> 2)) & 3) * 8;
  }

  float4v acc[4][4] = {};

  for (int k0 = 0; k0 < 1024; k0 += 32) {
    __syncthreads();
    async_copy16(ldsA,        Ag + k0);
    async_copy16(ldsA + 4096, Ag + k0 + 64 * 1024);
    async_copy16(ldsB,        Bg + k0);
    async_copy16(ldsB + 4096, Bg + k0 + 64 * 1024);
    __syncthreads();
    half8 af[4], bf[4];
#pragma unroll
    for (int i = 0; i < 4; i++) {
      af[i] = *(const half8*)(As + aoff[i]);
      bf[i] = *(const half8*)(Bs + boff[i]);
    }
#pragma unroll
    for (int mi = 0; mi < 4; mi++)
#pragma unroll
      for (int ni = 0; ni < 4; ni++)
        acc[mi][ni] = __builtin_amdgcn_mfma_f32_16x16x32_f16(af[mi], bf[ni], acc[mi][ni], 0, 0, 0);
  }

  // epilogue: C[row=(lane>>4)*4+r, col=lane&15] per 16x16 tile (m89-verified)
#pragma unroll
  for (int mi = 0; mi < 4; mi++) {
#pragma unroll
    for (int ni = 0; ni < 4; ni++) {
      int gm0 = mB * 128 + wm * 64 + mi * 16 + lq * 4;
      int gn  = nB * 128 + wn * 64 + ni * 16 + lr;
#pragma unroll
      for (int r = 0; r < 4; r++) {
        float v = acc[mi][ni][r];
        int gm = gm0 + r;
        if (EPI == 0) {
          int b = gm >> 11, l = gm & 2047, h = gn >> 6, d = gn & 63;
          ((_Float16*)Cout)[(((size_t)(b * Hc + h) * Lc + l) << 6) + d] = (_Float16)v;
        } else if (EPI == 1) {
          int b = gm >> 11, l = gm & 2047, h = gn >> 6, d = gn & 63;
          ((_Float16*)Cout)[(((size_t)(b * Hc + h) * Dc + d) << 11) + l] = (_Float16)v;
        } else {
          ((float*)Cout)[(size_t)gm * Ec + gn] = v;
        }
      }
    }
  }
}

// ---------------- fused causal attention ----------------
// grid (32, 64): x = 64-row block rb, y = bh. Block 256 thr = 4 waves,
// wave w owns rows [w*16, w*16+16) of the 64-row Q block.
// Pass 1: online row max/sum over K tiles. Pass 2: recompute S, write
// P=softmax fp32 to attn output, O += P@V via LDS round-trip.
__global__ __launch_bounds__(256, 2) void attn_fused(
    const _Float16* __restrict__ Qb, const _Float16* __restrict__ Kb,
    const _Float16* __restrict__ Vt, float* __restrict__ attn,
    _Float16* __restrict__ Ob) {
  __shared__ __align__(16) _Float16 Qs[64 * 72];  // 144B rows (pad breaks conflicts)
  __shared__ __align__(16) _Float16 Ks[64 * 72];
  __shared__ __align__(16) _Float16 Vs[64 * 72];  // Vt tile: row=d, col=j
  __shared__ __align__(16) float    Ps[64 * 68];  // 272B rows

  const int tid = threadIdx.x;
  const int w = tid >> 6, lane = tid & 63, lr = lane & 15, lq = lane >> 4;
  const int rb = blockIdx.x, bh = blockIdx.y;

  const _Float16* qbase = Qb + ((size_t)bh * Lc + rb * 64) * Dc;
  const _Float16* kbase = Kb + (size_t)bh * Lc * Dc;
  const _Float16* vbase = Vt + (size_t)bh * Dc * Lc;
  float* abase = attn + ((size_t)bh * Lc + (size_t)rb * 64) * Lc;

  // zero-fill fully-masked tiles (j >= (rb+1)*64): harness poisons d_out
  {
    int row = tid >> 2, cb = (tid & 3) * 16;
    float4v z = {0.f, 0.f, 0.f, 0.f};
    for (int jt = rb + 1; jt < 32; jt++) {
      float* dst = abase + (size_t)row * Lc + jt * 64 + cb;
#pragma unroll
      for (int k2 = 0; k2 < 4; k2++) ((float4v*)dst)[k2] = z;
    }
  }

  // stage Q once
#pragma unroll
  for (int i2 = 0; i2 < 2; i2++) {
    int qq = tid + i2 * 256;
    int row = qq >> 3, c = qq & 7;
    *(half8*)(Qs + row * 72 + c * 8) = *(const half8*)(qbase + (size_t)row * Dc + c * 8);
  }
  __syncthreads();
  half8 aq[2];
  aq[0] = *(const half8*)(Qs + (w * 16 + lr) * 72 + lq * 8);
  aq[1] = *(const half8*)(Qs + (w * 16 + lr) * 72 + 32 + lq * 8);

  float mrun[4], lrun[4];
#pragma unroll
  for (int r = 0; r < 4; r++) { mrun[r] = -1e30f; lrun[r] = 0.f; }
  const int il0 = w * 16 + lq * 4;  // local row base of this lane's 4 acc rows

  // ---- pass 1: stats ----
  for (int jt = 0; jt <= rb; jt++) {
    __syncthreads();
#pragma unroll
    for (int i2 = 0; i2 < 2; i2++) {
      int qq = tid + i2 * 256;
      int row = qq >> 3, c = qq & 7;
      *(half8*)(Ks + row * 72 + c * 8) =
          *(const half8*)(kbase + ((size_t)jt * 64 + row) * Dc + c * 8);
    }
    __syncthreads();
    float4v sc[4];
#pragma unroll
    for (int c = 0; c < 4; c++) {
      half8 bk0 = *(const half8*)(Ks + (c * 16 + lr) * 72 + lq * 8);
      half8 bk1 = *(const half8*)(Ks + (c * 16 + lr) * 72 + 32 + lq * 8);
      float4v t = {0.f, 0.f, 0.f, 0.f};
      t = __builtin_amdgcn_mfma_f32_16x16x32_f16(aq[0], bk0, t, 0, 0, 0);
      t = __builtin_amdgcn_mfma_f32_16x16x32_f16(aq[1], bk1, t, 0, 0, 0);
      t = t * 0.125f;  // 1/sqrt(64)
      if (jt == rb) {
        int jl = c * 16 + lr;
#pragma unroll
        for (int r = 0; r < 4; r++)
          if (jl > il0 + r) t[r] = -1e30f;
      }
      sc[c] = t;
    }
#pragma unroll
    for (int r = 0; r < 4; r++) {
      float mx = fmaxf(fmaxf(sc[0][r], sc[1][r]), fmaxf(sc[2][r], sc[3][r]));
#pragma unroll
      for (int off = 1; off < 16; off <<= 1) mx = fmaxf(mx, __shfl_xor(mx, off));
      float nm = fmaxf(mrun[r], mx);
      float sum = __expf(sc[0][r] - nm) + __expf(sc[1][r] - nm) +
                  __expf(sc[2][r] - nm) + __expf(sc[3][r] - nm);
#pragma unroll
      for (int off = 1; off < 16; off <<= 1) sum += __shfl_xor(sum, off);
      lrun[r] = lrun[r] * __expf(mrun[r] - nm) + sum;
      mrun[r] = nm;
    }
  }
  float linv[4];
#pragma unroll
  for (int r = 0; r < 4; r++) linv[r] = 1.f / lrun[r];

  float4v accO[4] = {};

  // ---- pass 2: P write + PV ----
  for (int jt = 0; jt <= rb; jt++) {
    __syncthreads();
#pragma unroll
    for (int i2 = 0; i2 < 2; i2++) {
      int qq = tid + i2 * 256;
      int row = qq >> 3, c = qq & 7;
      *(half8*)(Ks + row * 72 + c * 8) =
          *(const half8*)(kbase + ((size_t)jt * 64 + row) * Dc + c * 8);
      *(half8*)(Vs + row * 72 + c * 8) =
          *(const half8*)(vbase + (size_t)row * Lc + jt * 64 + c * 8);
    }
    __syncthreads();
#pragma unroll
    for (int c = 0; c < 4; c++) {
      half8 bk0 = *(const half8*)(Ks + (c * 16 + lr) * 72 + lq * 8);
      half8 bk1 = *(const half8*)(Ks + (c * 16 + lr) * 72 + 32 + lq * 8);
      float4v t = {0.f, 0.f, 0.f, 0.f};
      t = __builtin_amdgcn_mfma_f32_16x16x32_f16(aq[0], bk0, t, 0, 0, 0);
      t = __builtin_amdgcn_mfma_f32_16x16x32_f16(aq[1], bk1, t, 0, 0, 0);
      t = t * 0.125f;
      int jl = c * 16 + lr;
#pragma unroll
      for (int r = 0; r < 4; r++) {
        float sv = t[r];
        if (jt == rb && jl > il0 + r) sv = -1e30f;
        float p = __expf(sv - mrun[r]) * linv[r];
        Ps[(w * 16 + lq * 4 + r) * 68 + jl] = p;  // wave writes only its rows
      }
    }
    __syncthreads();
    // coalesced fp32 attn write from LDS
    {
      int row = tid >> 2, cb = (tid & 3) * 16;
      const float* srcp = Ps + row * 68 + cb;
      float* dst = abase + (size_t)row * Lc + jt * 64 + cb;
#pragma unroll
      for (int k2 = 0; k2 < 4; k2++) ((float4v*)dst)[k2] = ((const float4v*)srcp)[k2];
    }
    // PV: A-frag = P rows (C-layout -> A-layout via LDS), B-frag = Vt (n=d,k=j)
#pragma unroll
    for (int kc = 0; kc < 2; kc++) {
      const float* prow = Ps + (w * 16 + lr) * 68 + kc * 32 + lq * 8;
      float4v p0 = *(const float4v*)prow;
      float4v p1 = *(const float4v*)(prow + 4);
      half8 ap;
      ap[0] = (_Float16)p0[0]; ap[1] = (_Float16)p0[1];
      ap[2] = (_Float16)p0[2]; ap[3] = (_Float16)p0[3];
      ap[4] = (_Float16)p1[0]; ap[5] = (_Float16)p1[1];
      ap[6] = (_Float16)p1[2]; ap[7] = (_Float16)p1[3];
#pragma unroll
      for (int ni = 0; ni < 4; ni++) {
        half8 bv = *(const half8*)(Vs + (ni * 16 + lr) * 72 + kc * 32 + lq * 8);
        accO[ni] = __builtin_amdgcn_mfma_f32_16x16x32_f16(ap, bv, accO[ni], 0, 0, 0);
      }
    }
  }

  // write O to [b, l, h*64+d] fp16 (input layout for the output projection)
  {
    int b = bh >> 4, h = bh & 15;
#pragma unroll
    for (int ni = 0; ni < 4; ni++) {
#pragma unroll
      for (int r = 0; r < 4; r++) {
        int i = rb * 64 + w * 16 + lq * 4 + r;
        int d = h * 64 + ni * 16 + lr;
        Ob[((size_t)b * Lc + i) * Ec + d] = (_Float16)accO[ni][r];
      }
    }
  }
}

// ---------------- launcher ----------------
extern "C" void kernel_launch(void* const* d_in, const int* in_sizes, int n_in,
                              void* d_out, int out_size, void* d_ws, size_t ws_size,
                              hipStream_t stream) {
  const float* q  = (const float*)d_in[0];
  const float* k  = (const float*)d_in[1];
  const float* v  = (const float*)d_in[2];
  // d_in[3] = mask (causal, hardcoded)
  const float* Wq = (const float*)d_in[4];
  const float* Wk = (const float*)d_in[5];
  const float* Wv = (const float*)d_in[6];
  const float* Wo = (const float*)d_in[7];

  char* ws = (char*)d_ws;
  _Float16* qh  = (_Float16*)(ws + (size_t)0);
  _Float16* kh  = (_Float16*)(ws + (size_t)16777216);
  _Float16* vh  = (_Float16*)(ws + (size_t)33554432);
  _Float16* Wqh = (_Float16*)(ws + (size_t)50331648);
  _Float16* Wkh = (_Float16*)(ws + (size_t)52428800);
  _Float16* Wvh = (_Float16*)(ws + (size_t)54525952);
  _Float16* Woh = (_Float16*)(ws + (size_t)56623104);
  _Float16* Qb  = (_Float16*)(ws + (size_t)58720256);
  _Float16* Kb  = (_Float16*)(ws + (size_t)75497472);
  _Float16* Vt  = (_Float16*)(ws + (size_t)92274688);
  _Float16* Ob  = (_Float16*)(ws + (size_t)109051904);
  // total ws use: 120 MiB

  const int nqkv4 = Bc * Lc * Ec / 4;  // 2097152
  const int nw4   = Ec * Ec / 4;       // 262144
  cvt_kernel<<<nqkv4 / 256, 256, 0, stream>>>(q, qh, nqkv4);
  cvt_kernel<<<nqkv4 / 256, 256, 0, stream>>>(k, kh, nqkv4);
  cvt_kernel<<<nqkv4 / 256, 256, 0, stream>>>(v, vh, nqkv4);
  cvt_kernel<<<nw4 / 256, 256, 0, stream>>>(Wq, Wqh, nw4);
  cvt_kernel<<<nw4 / 256, 256, 0, stream>>>(Wk, Wkh, nw4);
  cvt_kernel<<<nw4 / 256, 256, 0, stream>>>(Wv, Wvh, nw4);
  cvt_kernel<<<nw4 / 256, 256, 0, stream>>>(Wo, Woh, nw4);

  dim3 gg(8, 64);  // nB x mB
  gemm_bt<0><<<gg, 256, 0, stream>>>(qh, Wqh, Qb);
  gemm_bt<0><<<gg, 256, 0, stream>>>(kh, Wkh, Kb);
  gemm_bt<1><<<gg, 256, 0, stream>>>(vh, Wvh, Vt);

  float* attn_out = (float*)d_out + (size_t)Bc * Lc * Ec;
  dim3 ga(32, 64);  // rb x bh
  attn_fused<<<ga, 256, 0, stream>>>(Qb, Kb, Vt, attn_out, Ob);

  gemm_bt<2><<<gg, 256, 0, stream>>>(Ob, Woh, (float*)d_out);
}